// Round 3
// baseline (70.336 us; speedup 1.0000x reference)
//
#include <hip/hip_runtime.h>
#include <math.h>

// CARAFE: features [2,64,64,128] f32, masks [2,128,128,25] f32 -> out [2,128,128,128] f32
// K=5, k2=25, G=1, Cg=128. Nearest upsample 64->128: each 2x2 output quad shares
// one low-res pixel (r,c) and its 25 patch vectors; only softmax weights differ.
//
// One 64-lane wave per quad, lane = channel pair (float2, 128 ch). The 4 softmaxes
// run as 2 rounds of 2 (lower wave half = quad row 0, upper half = row 1, width-32
// shfl reductions). Weights are hoisted to SGPRs with readlane (j is compile-time
// in the unrolled loop) so the inner loop is:
//   1 wave-uniform coalesced 512B global load + 8 v_fmac_f32 (SGPR multiplier).
// NOTE: __builtin_amdgcn_readlane is int-typed -> must BITCAST floats through it
// (a plain float argument is numerically converted to int == 0, which zeroed the
// whole output in the previous round).
// No barriers, no LDS -> waves drift freely, latency hides behind 24 waves/CU.
// XCD-chunked swizzle keeps each XCD's feature slice ~0.6 MB (L2-resident).

#define K  5
#define K2 25

typedef float v2f __attribute__((ext_vector_type(2)));

__device__ __forceinline__ float readlane_f32(float v, int l) {
    return __builtin_bit_cast(float,
        __builtin_amdgcn_readlane(__builtin_bit_cast(int, v), l));
}

__global__ __launch_bounds__(256, 6) void carafe_wave_kernel(
    const float* __restrict__ feat,   // [B,64,64,128]
    const float* __restrict__ masks,  // [B,128,128,25]
    float* __restrict__ out)          // [B,128,128,128]
{
    // XCD-chunked bijective swizzle: 2048 wgs, 8 XCDs -> 256-block contiguous chunks
    const int bid = blockIdx.x;
    const int wg  = (bid & 7) * (2048 >> 3) + (bid >> 3);

    const int wid  = __builtin_amdgcn_readfirstlane(threadIdx.x >> 6); // wave 0..3 (SGPR)
    const int lane = threadIdx.x & 63;
    const int half = lane >> 5;            // 0: quad row 0 (pix +0,+1), 1: row 1 (+128,+129)
    const int l32  = lane & 31;

    const int q   = wg * 4 + wid;          // quad id 0..8191, wave-uniform SGPR
    const int b   = q >> 12;               // / (64*64)
    const int rem = q & 4095;
    const int r   = rem >> 6;              // low-res row
    const int c   = rem & 63;              // low-res col

    const int pix00 = ((b * 128 + 2 * r) * 128 + 2 * c);

    // ---- 4 softmaxes as 2 rounds x 2 halves (width-32 reductions keep halves independent)
    float w[2];
    #pragma unroll
    for (int rnd = 0; rnd < 2; ++rnd) {
        const int pix = pix00 + half * 128 + rnd;     // quad pixel (half, rnd)
        float mv = (l32 < K2) ? masks[(size_t)pix * K2 + l32] : -INFINITY;
        float mx = mv;
        #pragma unroll
        for (int off = 16; off >= 1; off >>= 1)
            mx = fmaxf(mx, __shfl_xor(mx, off, 32));
        float e = (l32 < K2) ? __expf(mv - mx) : 0.0f;
        float s = e;
        #pragma unroll
        for (int off = 16; off >= 1; off >>= 1)
            s += __shfl_xor(s, off, 32);
        w[rnd] = e / s;                    // lane l32 holds weight of logit l32 (<25)
    }

    // ---- weighted patch accumulation: weights broadcast via readlane -> SGPR FMAs
    v2f acc0 = 0.f, acc1 = 0.f, acc2 = 0.f, acc3 = 0.f;
    const float* fb = feat + (size_t)b * (64 * 64 * 128) + lane * 2;

    #pragma unroll
    for (int di = 0; di < K; ++di) {
        const int rr = r + di - 2;
        if ((unsigned)rr >= 64u) continue;             // wave-uniform scalar branch
        #pragma unroll
        for (int dj = 0; dj < K; ++dj) {
            const int cc = c + dj - 2;
            if ((unsigned)cc >= 64u) continue;         // wave-uniform scalar branch
            const int j = di * K + dj;                 // compile-time after unroll
            const float w0 = readlane_f32(w[0], j);      // pix +0
            const float w1 = readlane_f32(w[1], j);      // pix +1
            const float w2 = readlane_f32(w[0], j + 32); // pix +128
            const float w3 = readlane_f32(w[1], j + 32); // pix +129
            const v2f f = *(const v2f*)(fb + (size_t)(rr * 64 + cc) * 128);
            acc0 += f * w0;
            acc1 += f * w1;
            acc2 += f * w2;
            acc3 += f * w3;
        }
    }

    // ---- 4 coalesced 512B stores
    float* ob = out + (size_t)pix00 * 128 + lane * 2;
    *(v2f*)(ob + 0)               = acc0;   // pix00
    *(v2f*)(ob + 128)             = acc1;   // pix00 + 1
    *(v2f*)(ob + 128 * 128)       = acc2;   // pix00 + 128
    *(v2f*)(ob + 128 * 128 + 128) = acc3;   // pix00 + 129
}

extern "C" void kernel_launch(void* const* d_in, const int* in_sizes, int n_in,
                              void* d_out, int out_size, void* d_ws, size_t ws_size,
                              hipStream_t stream) {
    const float* feat  = (const float*)d_in[0];   // 2*64*64*128
    const float* masks = (const float*)d_in[1];   // 2*128*128*25
    float* out = (float*)d_out;                   // 2*128*128*128

    // quads = B * 64 * 64 = 8192; 4 quads (4 waves, 256 threads) per block
    dim3 grid(8192 / 4), block(256);
    carafe_wave_kernel<<<grid, block, 0, stream>>>(feat, masks, out);
}

// Round 4
// 68.713 us; speedup vs baseline: 1.0236x; 1.0236x over previous
//
#include <hip/hip_runtime.h>
#include <math.h>

// CARAFE: features [2,64,64,128] f32, masks [2,128,128,25] f32 -> out [2,128,128,128] f32
// K=5, k2=25, G=1, Cg=128. Nearest upsample 64->128 half-pixel: src = dst>>1,
// so each 2x2 output quad shares one low-res pixel (r,c) and its 25 patch vectors.
//
// Best-measured structure (round 1, 68.7 us): each block (8 quads = one low-res row
// segment, cols c0..c0+7) stages its UNIQUE 5x12 footprint of feature pixels
// (60 pixels x 512 B = 30 KB, zero-padded at edges) into LDS with 8 coalesced
// float4 loads per thread, overlapped with the mask softmax. The j-loop is pure LDS:
//   1 broadcast ds_read_b128 (quad weights) + 1 contiguous ds_read_b128 (features)
//   + 8 v_pk_fma_f32, compile-time offsets, no bounds checks.
// LDS 30K + 3.2K = 33.3 KB -> 4 blocks/CU, grid 1024 = exactly 4 blocks/CU resident.
//
// This round adds the XCD-chunked bijective block swizzle (1024 % 8 == 0): each
// XCD gets a contiguous 128-block band of rows, so vertically-overlapping 5-row
// halos hit that XCD's L2 instead of re-fetching across XCDs.
//
// Session finding: dur_us is dominated by the harness's 256 MiB poison fill
// (~42 us @ 80% HBM peak, every top-5 rocprof row) + reset dispatch overhead;
// three structurally disjoint kernels measured within 1.8 us of each other.

#define K   5
#define K2  25
#define QPB 8              // quads per block (same r, consecutive c)
#define TW  (QPB + K - 1)  // 12 tile cols
#define TH  K              // 5  tile rows
#define NPIX (TH * TW)     // 60 staged pixels

typedef float v4f __attribute__((ext_vector_type(4)));

__global__ __launch_bounds__(256) void carafe_tile_kernel(
    const float* __restrict__ feat,   // [B,64,64,128]
    const float* __restrict__ masks,  // [B,128,128,25]
    float* __restrict__ out)          // [B,128,128,128]
{
    __shared__ v4f tile[TH][TW][32];  // 30 KB zero-padded feature tile
    __shared__ v4f wq[QPB][K2];       // 3.2 KB: [quad][j] -> weights of 4 quad pixels

    const int tid   = threadIdx.x;
    const int group = tid >> 5;       // quad slot 0..7 (also: pixel-stage slot)
    const int lane  = tid & 31;       // float4 channel slot (4 ch/lane)

    // XCD-chunked bijective swizzle: 1024 wgs, 8 XCDs -> 128-block contiguous chunks
    const int bid = blockIdx.x;
    const int wg  = (bid & 7) * (1024 >> 3) + (bid >> 3);

    const int q0  = wg * QPB;         // first quad of block (multiple of 8 -> same b,r)
    const int b   = q0 >> 12;         // / (64*64)
    const int rem = q0 & 4095;
    const int r   = rem >> 6;         // low-res row
    const int c0  = rem & 63;         // first low-res col (multiple of 8)

    // ---- issue the 8 coalesced feature-tile loads first (independent, in flight)
    const v4f* featv = (const v4f*)feat;          // 32 float4 per low-res pixel
    const size_t fbase = (size_t)b * (64 * 64 * 32);

    v4f stg[8];
    #pragma unroll
    for (int i = 0; i < 8; ++i) {
        const int p = group + i * 8;              // staged pixel 0..63 (need < 60)
        v4f v = 0.f;
        if (p < NPIX) {
            const int row = p / TW;               // 0..4
            const int col = p - row * TW;         // 0..11
            const int gr  = r  - 2 + row;
            const int gc  = c0 - 2 + col;
            if ((unsigned)gr < 64u && (unsigned)gc < 64u)
                v = featv[fbase + (size_t)(gr * 64 + gc) * 32 + lane];
        }
        stg[i] = v;                               // zero-padded at edges
    }

    // ---- 4 softmaxes over 25 mask logits (lane j holds logit j for j<25);
    //      mask-load latency hides under the feature loads above
    const int pix00 = ((b * 128 + 2 * r) * 128 + 2 * (c0 + group));
    const int pixofs[4] = {0, 1, 128, 129};

    float w[4];
    #pragma unroll
    for (int p = 0; p < 4; ++p) {
        const int pix = pix00 + pixofs[p];
        float mv = (lane < K2) ? masks[(size_t)pix * K2 + lane] : -INFINITY;
        float mx = mv;
        #pragma unroll
        for (int off = 16; off >= 1; off >>= 1)
            mx = fmaxf(mx, __shfl_xor(mx, off, 32));
        float e = (lane < K2) ? __expf(mv - mx) : 0.0f;
        float s = e;
        #pragma unroll
        for (int off = 16; off >= 1; off >>= 1)
            s += __shfl_xor(s, off, 32);
        w[p] = e / s;
    }

    // ---- commit staged tile + weights to LDS
    #pragma unroll
    for (int i = 0; i < 8; ++i) {
        const int p = group + i * 8;
        if (p < NPIX)
            ((v4f*)tile)[p * 32 + lane] = stg[i];  // contiguous 512B per half-wave
    }
    if (lane < K2) {
        float* dst = (float*)&wq[group][lane];
        dst[0] = w[0]; dst[1] = w[1]; dst[2] = w[2]; dst[3] = w[3];
    }
    __syncthreads();

    // ---- pure-LDS weighted accumulation: no bounds checks, immediate offsets
    v4f acc0 = 0.f, acc1 = 0.f, acc2 = 0.f, acc3 = 0.f;
    #pragma unroll
    for (int j = 0; j < K2; ++j) {
        const int di = j / K;
        const int dj = j % K;
        const v4f wj = wq[group][j];               // broadcast within 32-lane group
        const v4f f  = tile[di][group + dj][lane]; // contiguous b128, conflict-benign
        acc0 += f * wj.x;
        acc1 += f * wj.y;
        acc2 += f * wj.z;
        acc3 += f * wj.w;
    }

    // ---- write the 4 output pixels (512 B coalesced per group)
    v4f* outv = (v4f*)out;
    outv[(size_t)(pix00 +   0) * 32 + lane] = acc0;
    outv[(size_t)(pix00 +   1) * 32 + lane] = acc1;
    outv[(size_t)(pix00 + 128) * 32 + lane] = acc2;
    outv[(size_t)(pix00 + 129) * 32 + lane] = acc3;
}

extern "C" void kernel_launch(void* const* d_in, const int* in_sizes, int n_in,
                              void* d_out, int out_size, void* d_ws, size_t ws_size,
                              hipStream_t stream) {
    const float* feat  = (const float*)d_in[0];   // 2*64*64*128
    const float* masks = (const float*)d_in[1];   // 2*128*128*25
    float* out = (float*)d_out;                   // 2*128*128*128

    // quads = B * 64 * 64 = 8192; 8 quads (256 threads) per block
    dim3 grid((2 * 64 * 64) / QPB), block(256);
    carafe_tile_kernel<<<grid, block, 0, stream>>>(feat, masks, out);
}